// Round 12
// baseline (23.963 us; speedup 1.0000x reference)
//
#include <hip/hip_runtime.h>
#include <math.h>

constexpr int BB   = 2;
constexpr int NN   = 512;
constexpr int FIN  = 256;
constexpr int FOUT = 128;

// ---------------------------------------------------------------------------
// Kernel A: Wh = x@W, u half-dots.  (FROZEN R10 winner)
// 512 blocks = (256 row-groups of 4) x (2 o-halves) x 256 thr.
// ---------------------------------------------------------------------------
__global__ __launch_bounds__(256) void wh_u_kernel(const float* __restrict__ x,
                                                   const float* __restrict__ W,
                                                   const float* __restrict__ a_fc,
                                                   float* __restrict__ Wh,
                                                   float* __restrict__ u2) {
    __shared__ float  xs[4 * FIN];
    __shared__ float4 part[4][16][17];

    const int t  = threadIdx.x;
    const int rg = blockIdx.x & 255;
    const int oh = blockIdx.x >> 8;
    const int g0 = rg * 4;

    ((float4*)xs)[t] = ((const float4*)(x + (size_t)g0 * FIN))[t];
    __syncthreads();

    const int og = t & 15;
    const int fs = t >> 4;
    const float* xr = xs + fs * 16;
    const float4* W4 = (const float4*)W;
    const int ob = oh * 16 + og;

    float4 a0 = {0.f,0.f,0.f,0.f}, a1 = {0.f,0.f,0.f,0.f};
    float4 a2 = {0.f,0.f,0.f,0.f}, a3 = {0.f,0.f,0.f,0.f};
#pragma unroll
    for (int f = 0; f < 16; ++f) {
        const float4 wv = W4[(size_t)(fs * 16 + f) * 32 + ob];
        const float v0 = xr[f];
        const float v1 = xr[FIN + f];
        const float v2 = xr[2 * FIN + f];
        const float v3 = xr[3 * FIN + f];
        a0.x = fmaf(v0, wv.x, a0.x); a1.x = fmaf(v1, wv.x, a1.x);
        a2.x = fmaf(v2, wv.x, a2.x); a3.x = fmaf(v3, wv.x, a3.x);
        a0.y = fmaf(v0, wv.y, a0.y); a1.y = fmaf(v1, wv.y, a1.y);
        a2.y = fmaf(v2, wv.y, a2.y); a3.y = fmaf(v3, wv.y, a3.y);
        a0.z = fmaf(v0, wv.z, a0.z); a1.z = fmaf(v1, wv.z, a1.z);
        a2.z = fmaf(v2, wv.z, a2.z); a3.z = fmaf(v3, wv.z, a3.z);
        a0.w = fmaf(v0, wv.w, a0.w); a1.w = fmaf(v1, wv.w, a1.w);
        a2.w = fmaf(v2, wv.w, a2.w); a3.w = fmaf(v3, wv.w, a3.w);
    }
    part[0][fs][og] = a0;
    part[1][fs][og] = a1;
    part[2][fs][og] = a2;
    part[3][fs][og] = a3;
    __syncthreads();

    if (t < 64) {
        const int rl = t >> 4;
        const int o4 = t & 15;
        float4 s = {0.f, 0.f, 0.f, 0.f};
#pragma unroll
        for (int k = 0; k < 16; ++k) {
            const float4 pk = part[rl][k][o4];
            s.x += pk.x; s.y += pk.y; s.z += pk.z; s.w += pk.w;
        }
        ((float4*)(Wh + (size_t)(g0 + rl) * FOUT))[oh * 16 + o4] = s;

        const float4 a4 = ((const float4*)a_fc)[oh * 16 + o4];
        float pa = s.x * a4.x + s.y * a4.y + s.z * a4.z + s.w * a4.w;
        pa += __shfl_down(pa, 8, 16);
        pa += __shfl_down(pa, 4, 16);
        pa += __shfl_down(pa, 2, 16);
        pa += __shfl_down(pa, 1, 16);
        if (o4 == 0) u2[(size_t)oh * 1024 + g0 + rl] = pa;
    }
}

// ---------------------------------------------------------------------------
// Kernel B: e + sumsq partials, symmetric 16x16 tiles.  (FROZEN R11 winner)
// 1056 blocks x 256 thr, upper-triangular tile set J >= I + mirror writes.
// ---------------------------------------------------------------------------
__global__ __launch_bounds__(256) void e_kernel(const float* __restrict__ Wh,
                                                const float* __restrict__ u2,
                                                const float* __restrict__ a_fc,
                                                float* __restrict__ e_buf,
                                                float* __restrict__ partials) {
    __shared__ float whi[16][132];
    __shared__ float whj[16][132];
    __shared__ float a2s[FOUT];
    __shared__ float usi[16];
    __shared__ float usj[16];
    __shared__ float parts[16][4][17];
    __shared__ float red[4];

    const int t = threadIdx.x;
    int s = blockIdx.x;
    int b = 0;
    if (s >= 528) { b = 1; s -= 528; }
    int I = (int)(32.5f - sqrtf(1056.25f - 2.0f * (float)s));
    int PI = 32 * I - (I * (I - 1)) / 2;
    if (s < PI)                 { --I; PI = 32 * I - (I * (I - 1)) / 2; }
    else if (s >= PI + 32 - I)  { PI += 32 - I; ++I; }
    const int J    = I + (s - PI);
    const int bi0  = I * 16, bj0 = J * 16;
    const bool mir = (J > I);

    const float* whb = Wh + (size_t)(b * NN) * FOUT;

#pragma unroll
    for (int it = 0; it < 2; ++it) {
        const int idx = it * 256 + t;
        const int row = idx >> 5, c4 = idx & 31;
        *(float4*)&whi[row][c4 * 4] =
            *(const float4*)(whb + (size_t)(bi0 + row) * FOUT + c4 * 4);
        *(float4*)&whj[row][c4 * 4] =
            *(const float4*)(whb + (size_t)(bj0 + row) * FOUT + c4 * 4);
    }
    if (t < 16)
        usi[t] = u2[b * NN + bi0 + t] + u2[1024 + b * NN + bi0 + t];
    else if (t < 32)
        usj[t - 16] = u2[b * NN + bj0 + (t - 16)] +
                      u2[1024 + b * NN + bj0 + (t - 16)];
    else if (t >= 128)
        a2s[t - 128] = 0.4f * a_fc[t - 128];
    __syncthreads();

    const int w    = t >> 6;
    const int lane = t & 63;
    const int i    = lane & 15;
    const int jg   = lane >> 4;
    const int ob   = w * 32;

    float4 iv[8], av[8];
#pragma unroll
    for (int k = 0; k < 8; ++k) {
        iv[k] = *(const float4*)&whi[i][ob + 4 * k];
        av[k] = *(const float4*)&a2s[ob + 4 * k];
    }

#pragma unroll
    for (int jj = 0; jj < 4; ++jj) {
        const int j = jg * 4 + jj;
        float4 acc = {0.f, 0.f, 0.f, 0.f};
#pragma unroll
        for (int k = 0; k < 8; ++k) {
            const float4 jv = *(const float4*)&whj[j][ob + 4 * k];
            float sv;
            sv = iv[k].x + jv.x; acc.x = fmaf(av[k].x, fabsf(sv), acc.x);
            sv = iv[k].y + jv.y; acc.y = fmaf(av[k].y, fabsf(sv), acc.y);
            sv = iv[k].z + jv.z; acc.z = fmaf(av[k].z, fabsf(sv), acc.z);
            sv = iv[k].w + jv.w; acc.w = fmaf(av[k].w, fabsf(sv), acc.w);
        }
        parts[j][w][i] = (acc.x + acc.y) + (acc.z + acc.w);
    }
    __syncthreads();

    const int ci = t >> 4;
    const int cj = t & 15;
    const float S = (parts[cj][0][ci] + parts[cj][1][ci]) +
                    (parts[cj][2][ci] + parts[cj][3][ci]);
    const float v = fmaf(0.6f, usi[ci] + usj[cj], S);
    float ss = v * v;
    e_buf[(size_t)(b * NN + bi0 + ci) * NN + bj0 + cj] = v;
    if (mir) {
        e_buf[(size_t)(b * NN + bj0 + cj) * NN + bi0 + ci] = v;
        ss += ss;
    }

#pragma unroll
    for (int off = 32; off; off >>= 1) ss += __shfl_down(ss, off);
    if ((t & 63) == 0) red[t >> 6] = ss;
    __syncthreads();
    if (t == 0)
        partials[blockIdx.x] = (red[0] + red[1]) + (red[2] + red[3]);
}

// ---------------------------------------------------------------------------
// Kernel C: norm -> mask -> softmax -> att@Wh -> elu
// NEW: 2048 blocks x 256 thr: (2 rows) x (32-o quarter) -> 8 blocks/CU =
// 32 waves/CU (hardware max TLP). Softmax on waves 0-1 only (one per row);
// PV j-partition and combine tree bit-identical to R11 -> same numerics.
// ---------------------------------------------------------------------------
__global__ __launch_bounds__(256) void softmax_pv_kernel(
        const float* __restrict__ e_buf, const int* __restrict__ adj,
        const float* __restrict__ Wh, const float* __restrict__ partials,
        float* __restrict__ out) {
    __shared__ float p[2][NN];        // 4 KB
    __shared__ float hb[8][2][32];    // 2 KB
    __shared__ float red[4];
    __shared__ float rsv[2];

    const int t    = threadIdx.x;
    const int w    = t >> 6;
    const int lane = t & 63;

    // global Frobenius norm from 1056 partials
    float v = (partials[t] + partials[t + 256]) +
              (partials[t + 512] + partials[t + 768]);
    if (t < 32) v += partials[t + 1024];
#pragma unroll
    for (int off = 32; off; off >>= 1) v += __shfl_down(v, off);
    if (lane == 0) red[w] = v;
    __syncthreads();
    const float inv_norm = 1.0f / sqrtf((red[0] + red[1]) + (red[2] + red[3]));

    const int g0 = (blockIdx.x & 511) * 2;    // row pair (same batch: g0 even)
    const int oq = blockIdx.x >> 9;           // 0..3 o-quarter

    // --- softmax: wave w in {0,1} owns row g0+w (8 elems/lane, pure shfl) ---
    if (w < 2) {
        const int row = g0 + w;
        const float4* er4 = (const float4*)(e_buf + (size_t)row * NN);
        const int4*   ad4 = (const int4*)(adj + (size_t)row * NN);
        const float4 ea = er4[lane],     eb = er4[lane + 64];
        const int4   aa = ad4[lane],     ab = ad4[lane + 64];

        float va[8];
        va[0] = aa.x ? ea.x * inv_norm : -INFINITY;
        va[1] = aa.y ? ea.y * inv_norm : -INFINITY;
        va[2] = aa.z ? ea.z * inv_norm : -INFINITY;
        va[3] = aa.w ? ea.w * inv_norm : -INFINITY;
        va[4] = ab.x ? eb.x * inv_norm : -INFINITY;
        va[5] = ab.y ? eb.y * inv_norm : -INFINITY;
        va[6] = ab.z ? eb.z * inv_norm : -INFINITY;
        va[7] = ab.w ? eb.w * inv_norm : -INFINITY;

        float mx = va[0];
#pragma unroll
        for (int c = 1; c < 8; ++c) mx = fmaxf(mx, va[c]);
#pragma unroll
        for (int off = 32; off; off >>= 1) mx = fmaxf(mx, __shfl_xor(mx, off));

        float pv[8], sum = 0.f;
#pragma unroll
        for (int c = 0; c < 8; ++c) { pv[c] = expf(va[c] - mx); sum += pv[c]; }
        float4 pa = {pv[0], pv[1], pv[2], pv[3]};
        float4 pb = {pv[4], pv[5], pv[6], pv[7]};
        ((float4*)&p[w][0])[lane]      = pa;
        ((float4*)&p[w][0])[lane + 64] = pb;

#pragma unroll
        for (int off = 32; off; off >>= 1) sum += __shfl_xor(sum, off);
        if (lane == 0) rsv[w] = 1.0f / sum;
    }
    __syncthreads();

    // --- PV: o = oq*32 + (t&31); j-chunk jc = t>>5 (8 chunks of 64 j) ---
    const int oo = t & 31;
    const int o  = oq * 32 + oo;
    const int jc = t >> 5;
    const int b  = g0 >> 9;
    const float* whb = Wh + (size_t)(b * NN) * FOUT;
    const int j0 = jc * 64;

    float acc0 = 0.f, acc1 = 0.f;
    for (int j = j0; j < j0 + 64; j += 4) {
        const float4 p0 = *(const float4*)&p[0][j];
        const float4 p1 = *(const float4*)&p[1][j];
        float wv;
        wv = whb[(size_t)(j + 0) * FOUT + o];
        acc0 = fmaf(p0.x, wv, acc0); acc1 = fmaf(p1.x, wv, acc1);
        wv = whb[(size_t)(j + 1) * FOUT + o];
        acc0 = fmaf(p0.y, wv, acc0); acc1 = fmaf(p1.y, wv, acc1);
        wv = whb[(size_t)(j + 2) * FOUT + o];
        acc0 = fmaf(p0.z, wv, acc0); acc1 = fmaf(p1.z, wv, acc1);
        wv = whb[(size_t)(j + 3) * FOUT + o];
        acc0 = fmaf(p0.w, wv, acc0); acc1 = fmaf(p1.w, wv, acc1);
    }

    hb[jc][0][oo] = acc0;
    hb[jc][1][oo] = acc1;
    __syncthreads();

    if (t < 64) {
        const int r  = t >> 5;    // row 0..1
        const int o2 = t & 31;
        float h = ((hb[0][r][o2] + hb[1][r][o2]) + (hb[2][r][o2] + hb[3][r][o2])) +
                  ((hb[4][r][o2] + hb[5][r][o2]) + (hb[6][r][o2] + hb[7][r][o2]));
        h *= rsv[r];
        out[(size_t)(g0 + r) * FOUT + oq * 32 + o2] = (h > 0.f) ? h : expm1f(h);
    }
}

// ---------------------------------------------------------------------------
extern "C" void kernel_launch(void* const* d_in, const int* in_sizes, int n_in,
                              void* d_out, int out_size, void* d_ws, size_t ws_size,
                              hipStream_t stream) {
    const float* x    = (const float*)d_in[0];
    const int*   adj  = (const int*)d_in[1];
    const float* W    = (const float*)d_in[2];
    const float* a_fc = (const float*)d_in[3];
    float* out = (float*)d_out;

    float* ws       = (float*)d_ws;
    float* Wh       = ws;                         // 131072 floats
    float* u2       = ws + 131072;                // 2048
    float* partials = ws + 131072 + 2048;         // 1280 (1056 used)
    float* e_buf    = ws + 131072 + 2048 + 1280;  // 524288

    wh_u_kernel<<<dim3(512), dim3(256), 0, stream>>>(x, W, a_fc, Wh, u2);
    e_kernel<<<dim3(1056), dim3(256), 0, stream>>>(Wh, u2, a_fc, e_buf, partials);
    softmax_pv_kernel<<<dim3(2048), dim3(256), 0, stream>>>(e_buf, adj, Wh, partials, out);
}

// Round 13
// 23.938 us; speedup vs baseline: 1.0010x; 1.0010x over previous
//
#include <hip/hip_runtime.h>
#include <math.h>

constexpr int BB   = 2;
constexpr int NN   = 512;
constexpr int FIN  = 256;
constexpr int FOUT = 128;

// ---------------------------------------------------------------------------
// Kernel A: Wh = x@W, u half-dots.  (FROZEN R10 winner)
// 512 blocks = (256 row-groups of 4) x (2 o-halves) x 256 thr.
// ---------------------------------------------------------------------------
__global__ __launch_bounds__(256) void wh_u_kernel(const float* __restrict__ x,
                                                   const float* __restrict__ W,
                                                   const float* __restrict__ a_fc,
                                                   float* __restrict__ Wh,
                                                   float* __restrict__ u2) {
    __shared__ float  xs[4 * FIN];
    __shared__ float4 part[4][16][17];

    const int t  = threadIdx.x;
    const int rg = blockIdx.x & 255;
    const int oh = blockIdx.x >> 8;
    const int g0 = rg * 4;

    ((float4*)xs)[t] = ((const float4*)(x + (size_t)g0 * FIN))[t];
    __syncthreads();

    const int og = t & 15;
    const int fs = t >> 4;
    const float* xr = xs + fs * 16;
    const float4* W4 = (const float4*)W;
    const int ob = oh * 16 + og;

    float4 a0 = {0.f,0.f,0.f,0.f}, a1 = {0.f,0.f,0.f,0.f};
    float4 a2 = {0.f,0.f,0.f,0.f}, a3 = {0.f,0.f,0.f,0.f};
#pragma unroll
    for (int f = 0; f < 16; ++f) {
        const float4 wv = W4[(size_t)(fs * 16 + f) * 32 + ob];
        const float v0 = xr[f];
        const float v1 = xr[FIN + f];
        const float v2 = xr[2 * FIN + f];
        const float v3 = xr[3 * FIN + f];
        a0.x = fmaf(v0, wv.x, a0.x); a1.x = fmaf(v1, wv.x, a1.x);
        a2.x = fmaf(v2, wv.x, a2.x); a3.x = fmaf(v3, wv.x, a3.x);
        a0.y = fmaf(v0, wv.y, a0.y); a1.y = fmaf(v1, wv.y, a1.y);
        a2.y = fmaf(v2, wv.y, a2.y); a3.y = fmaf(v3, wv.y, a3.y);
        a0.z = fmaf(v0, wv.z, a0.z); a1.z = fmaf(v1, wv.z, a1.z);
        a2.z = fmaf(v2, wv.z, a2.z); a3.z = fmaf(v3, wv.z, a3.z);
        a0.w = fmaf(v0, wv.w, a0.w); a1.w = fmaf(v1, wv.w, a1.w);
        a2.w = fmaf(v2, wv.w, a2.w); a3.w = fmaf(v3, wv.w, a3.w);
    }
    part[0][fs][og] = a0;
    part[1][fs][og] = a1;
    part[2][fs][og] = a2;
    part[3][fs][og] = a3;
    __syncthreads();

    if (t < 64) {
        const int rl = t >> 4;
        const int o4 = t & 15;
        float4 s = {0.f, 0.f, 0.f, 0.f};
#pragma unroll
        for (int k = 0; k < 16; ++k) {
            const float4 pk = part[rl][k][o4];
            s.x += pk.x; s.y += pk.y; s.z += pk.z; s.w += pk.w;
        }
        ((float4*)(Wh + (size_t)(g0 + rl) * FOUT))[oh * 16 + o4] = s;

        const float4 a4 = ((const float4*)a_fc)[oh * 16 + o4];
        float pa = s.x * a4.x + s.y * a4.y + s.z * a4.z + s.w * a4.w;
        pa += __shfl_down(pa, 8, 16);
        pa += __shfl_down(pa, 4, 16);
        pa += __shfl_down(pa, 2, 16);
        pa += __shfl_down(pa, 1, 16);
        if (o4 == 0) u2[(size_t)oh * 1024 + g0 + rl] = pa;
    }
}

// ---------------------------------------------------------------------------
// Kernel B: e + sumsq partials, symmetric 16x16 tiles.  (FROZEN R11 winner)
// 1056 blocks x 256 thr, upper-triangular tile set J >= I + mirror writes.
// ---------------------------------------------------------------------------
__global__ __launch_bounds__(256) void e_kernel(const float* __restrict__ Wh,
                                                const float* __restrict__ u2,
                                                const float* __restrict__ a_fc,
                                                float* __restrict__ e_buf,
                                                float* __restrict__ partials) {
    __shared__ float whi[16][132];
    __shared__ float whj[16][132];
    __shared__ float a2s[FOUT];
    __shared__ float usi[16];
    __shared__ float usj[16];
    __shared__ float parts[16][4][17];
    __shared__ float red[4];

    const int t = threadIdx.x;
    int s = blockIdx.x;
    int b = 0;
    if (s >= 528) { b = 1; s -= 528; }
    int I = (int)(32.5f - sqrtf(1056.25f - 2.0f * (float)s));
    int PI = 32 * I - (I * (I - 1)) / 2;
    if (s < PI)                 { --I; PI = 32 * I - (I * (I - 1)) / 2; }
    else if (s >= PI + 32 - I)  { PI += 32 - I; ++I; }
    const int J    = I + (s - PI);
    const int bi0  = I * 16, bj0 = J * 16;
    const bool mir = (J > I);

    const float* whb = Wh + (size_t)(b * NN) * FOUT;

#pragma unroll
    for (int it = 0; it < 2; ++it) {
        const int idx = it * 256 + t;
        const int row = idx >> 5, c4 = idx & 31;
        *(float4*)&whi[row][c4 * 4] =
            *(const float4*)(whb + (size_t)(bi0 + row) * FOUT + c4 * 4);
        *(float4*)&whj[row][c4 * 4] =
            *(const float4*)(whb + (size_t)(bj0 + row) * FOUT + c4 * 4);
    }
    if (t < 16)
        usi[t] = u2[b * NN + bi0 + t] + u2[1024 + b * NN + bi0 + t];
    else if (t < 32)
        usj[t - 16] = u2[b * NN + bj0 + (t - 16)] +
                      u2[1024 + b * NN + bj0 + (t - 16)];
    else if (t >= 128)
        a2s[t - 128] = 0.4f * a_fc[t - 128];
    __syncthreads();

    const int w    = t >> 6;
    const int lane = t & 63;
    const int i    = lane & 15;
    const int jg   = lane >> 4;
    const int ob   = w * 32;

    float4 iv[8], av[8];
#pragma unroll
    for (int k = 0; k < 8; ++k) {
        iv[k] = *(const float4*)&whi[i][ob + 4 * k];
        av[k] = *(const float4*)&a2s[ob + 4 * k];
    }

#pragma unroll
    for (int jj = 0; jj < 4; ++jj) {
        const int j = jg * 4 + jj;
        float4 acc = {0.f, 0.f, 0.f, 0.f};
#pragma unroll
        for (int k = 0; k < 8; ++k) {
            const float4 jv = *(const float4*)&whj[j][ob + 4 * k];
            float sv;
            sv = iv[k].x + jv.x; acc.x = fmaf(av[k].x, fabsf(sv), acc.x);
            sv = iv[k].y + jv.y; acc.y = fmaf(av[k].y, fabsf(sv), acc.y);
            sv = iv[k].z + jv.z; acc.z = fmaf(av[k].z, fabsf(sv), acc.z);
            sv = iv[k].w + jv.w; acc.w = fmaf(av[k].w, fabsf(sv), acc.w);
        }
        parts[j][w][i] = (acc.x + acc.y) + (acc.z + acc.w);
    }
    __syncthreads();

    const int ci = t >> 4;
    const int cj = t & 15;
    const float S = (parts[cj][0][ci] + parts[cj][1][ci]) +
                    (parts[cj][2][ci] + parts[cj][3][ci]);
    const float v = fmaf(0.6f, usi[ci] + usj[cj], S);
    float ss = v * v;
    e_buf[(size_t)(b * NN + bi0 + ci) * NN + bj0 + cj] = v;
    if (mir) {
        e_buf[(size_t)(b * NN + bj0 + cj) * NN + bi0 + ci] = v;
        ss += ss;
    }

#pragma unroll
    for (int off = 32; off; off >>= 1) ss += __shfl_down(ss, off);
    if ((t & 63) == 0) red[t >> 6] = ss;
    __syncthreads();
    if (t == 0)
        partials[blockIdx.x] = (red[0] + red[1]) + (red[2] + red[3]);
}

// ---------------------------------------------------------------------------
// Kernel C: norm -> mask -> softmax -> att@Wh -> elu  (FROZEN R11 winner)
// 1024 blocks x 256 thr: (4 rows) x (32-o quarter), 4 blocks/CU.
// ---------------------------------------------------------------------------
__global__ __launch_bounds__(256) void softmax_pv_kernel(
        const float* __restrict__ e_buf, const int* __restrict__ adj,
        const float* __restrict__ Wh, const float* __restrict__ partials,
        float* __restrict__ out) {
    __shared__ float p[4][NN];
    __shared__ float hb[8][4][32];
    __shared__ float red[4];
    __shared__ float rsv[4];

    const int t    = threadIdx.x;
    const int w    = t >> 6;
    const int lane = t & 63;

    // global Frobenius norm from 1056 partials
    float v = (partials[t] + partials[t + 256]) +
              (partials[t + 512] + partials[t + 768]);
    if (t < 32) v += partials[t + 1024];
#pragma unroll
    for (int off = 32; off; off >>= 1) v += __shfl_down(v, off);
    if (lane == 0) red[w] = v;
    __syncthreads();
    const float inv_norm = 1.0f / sqrtf((red[0] + red[1]) + (red[2] + red[3]));

    const int g0  = (blockIdx.x & 255) * 4;
    const int oq  = blockIdx.x >> 8;
    const int row = g0 + w;

    const float4* er4 = (const float4*)(e_buf + (size_t)row * NN);
    const int4*   ad4 = (const int4*)(adj + (size_t)row * NN);
    const float4 ea = er4[lane],     eb = er4[lane + 64];
    const int4   aa = ad4[lane],     ab = ad4[lane + 64];

    float va[8];
    va[0] = aa.x ? ea.x * inv_norm : -INFINITY;
    va[1] = aa.y ? ea.y * inv_norm : -INFINITY;
    va[2] = aa.z ? ea.z * inv_norm : -INFINITY;
    va[3] = aa.w ? ea.w * inv_norm : -INFINITY;
    va[4] = ab.x ? eb.x * inv_norm : -INFINITY;
    va[5] = ab.y ? eb.y * inv_norm : -INFINITY;
    va[6] = ab.z ? eb.z * inv_norm : -INFINITY;
    va[7] = ab.w ? eb.w * inv_norm : -INFINITY;

    float mx = va[0];
#pragma unroll
    for (int c = 1; c < 8; ++c) mx = fmaxf(mx, va[c]);
#pragma unroll
    for (int off = 32; off; off >>= 1) mx = fmaxf(mx, __shfl_xor(mx, off));

    float pv[8], sum = 0.f;
#pragma unroll
    for (int c = 0; c < 8; ++c) { pv[c] = expf(va[c] - mx); sum += pv[c]; }
    float4 pa = {pv[0], pv[1], pv[2], pv[3]};
    float4 pb = {pv[4], pv[5], pv[6], pv[7]};
    ((float4*)&p[w][0])[lane]      = pa;
    ((float4*)&p[w][0])[lane + 64] = pb;

#pragma unroll
    for (int off = 32; off; off >>= 1) sum += __shfl_xor(sum, off);
    if (lane == 0) rsv[w] = 1.0f / sum;
    __syncthreads();

    const int oo = lane & 31;
    const int o  = oq * 32 + oo;
    const int jc = (w << 1) | (lane >> 5);
    const int b  = g0 >> 9;
    const float* whb = Wh + (size_t)(b * NN) * FOUT;
    const int j0 = jc * 64;

    float acc0 = 0.f, acc1 = 0.f, acc2 = 0.f, acc3 = 0.f;
    for (int j = j0; j < j0 + 64; j += 4) {
        const float4 p0 = *(const float4*)&p[0][j];
        const float4 p1 = *(const float4*)&p[1][j];
        const float4 p2 = *(const float4*)&p[2][j];
        const float4 p3 = *(const float4*)&p[3][j];
        float wv;
        wv = whb[(size_t)(j + 0) * FOUT + o];
        acc0 = fmaf(p0.x, wv, acc0); acc1 = fmaf(p1.x, wv, acc1);
        acc2 = fmaf(p2.x, wv, acc2); acc3 = fmaf(p3.x, wv, acc3);
        wv = whb[(size_t)(j + 1) * FOUT + o];
        acc0 = fmaf(p0.y, wv, acc0); acc1 = fmaf(p1.y, wv, acc1);
        acc2 = fmaf(p2.y, wv, acc2); acc3 = fmaf(p3.y, wv, acc3);
        wv = whb[(size_t)(j + 2) * FOUT + o];
        acc0 = fmaf(p0.z, wv, acc0); acc1 = fmaf(p1.z, wv, acc1);
        acc2 = fmaf(p2.z, wv, acc2); acc3 = fmaf(p3.z, wv, acc3);
        wv = whb[(size_t)(j + 3) * FOUT + o];
        acc0 = fmaf(p0.w, wv, acc0); acc1 = fmaf(p1.w, wv, acc1);
        acc2 = fmaf(p2.w, wv, acc2); acc3 = fmaf(p3.w, wv, acc3);
    }

    hb[jc][0][oo] = acc0;
    hb[jc][1][oo] = acc1;
    hb[jc][2][oo] = acc2;
    hb[jc][3][oo] = acc3;
    __syncthreads();

    if (t < 128) {
        const int r  = t >> 5;
        const int o2 = t & 31;
        float h = ((hb[0][r][o2] + hb[1][r][o2]) + (hb[2][r][o2] + hb[3][r][o2])) +
                  ((hb[4][r][o2] + hb[5][r][o2]) + (hb[6][r][o2] + hb[7][r][o2]));
        h *= rsv[r];
        out[(size_t)(g0 + r) * FOUT + oq * 32 + o2] = (h > 0.f) ? h : expm1f(h);
    }
}

// ---------------------------------------------------------------------------
extern "C" void kernel_launch(void* const* d_in, const int* in_sizes, int n_in,
                              void* d_out, int out_size, void* d_ws, size_t ws_size,
                              hipStream_t stream) {
    const float* x    = (const float*)d_in[0];
    const int*   adj  = (const int*)d_in[1];
    const float* W    = (const float*)d_in[2];
    const float* a_fc = (const float*)d_in[3];
    float* out = (float*)d_out;

    float* ws       = (float*)d_ws;
    float* Wh       = ws;                         // 131072 floats
    float* u2       = ws + 131072;                // 2048
    float* partials = ws + 131072 + 2048;         // 1280 (1056 used)
    float* e_buf    = ws + 131072 + 2048 + 1280;  // 524288

    wh_u_kernel<<<dim3(512), dim3(256), 0, stream>>>(x, W, a_fc, Wh, u2);
    e_kernel<<<dim3(1056), dim3(256), 0, stream>>>(Wh, u2, a_fc, e_buf, partials);
    softmax_pv_kernel<<<dim3(1024), dim3(256), 0, stream>>>(e_buf, adj, Wh, partials, out);
}